// Round 1
// baseline (5514.183 us; speedup 1.0000x reference)
//
#include <hip/hip_runtime.h>
#include <math.h>

// Problem constants (from reference): B=4, S=1024, D=1024, H=16, DH=64, E=8, FF=2048
#define B_   4
#define S_   1024
#define D_   1024
#define H_   16
#define DH_  64
#define E_   8
#define FF_  2048
#define M_   (B_ * S_)     // 4096 rows
#define EPS_ 1e-5f

// ============================================================================
// GEMM 1: C[M,N] = A[M,K] @ W[N,K]^T + bias[N]   (qkv proj, out proj)
// 128x128 tile, BK=16, 256 threads, 8x8 micro-tile. LDS stored k-major
// (transposed) so fragment reads are ds_read_b128.
// ============================================================================
__global__ __launch_bounds__(256) void gemm_bt(
    const float* __restrict__ A, const float* __restrict__ W,
    const float* __restrict__ bias, float* __restrict__ C, int N, int K) {
  __shared__ float As[16][132];
  __shared__ float Bs[16][132];
  const int tid = threadIdx.x;
  const int tx = tid & 15, ty = tid >> 4;
  const int m0 = blockIdx.y * 128, n0 = blockIdx.x * 128;
  const int ar = tid >> 2, ak = (tid & 3) * 4;  // row 0..63, k-chunk
  float acc[8][8] = {};
  for (int k0 = 0; k0 < K; k0 += 16) {
    float4 a0 = *(const float4*)&A[(size_t)(m0 + ar) * K + k0 + ak];
    float4 a1 = *(const float4*)&A[(size_t)(m0 + ar + 64) * K + k0 + ak];
    float4 w0 = *(const float4*)&W[(size_t)(n0 + ar) * K + k0 + ak];
    float4 w1 = *(const float4*)&W[(size_t)(n0 + ar + 64) * K + k0 + ak];
    __syncthreads();  // previous iteration's compute done before overwrite
    As[ak+0][ar]    = a0.x; As[ak+1][ar]    = a0.y; As[ak+2][ar]    = a0.z; As[ak+3][ar]    = a0.w;
    As[ak+0][ar+64] = a1.x; As[ak+1][ar+64] = a1.y; As[ak+2][ar+64] = a1.z; As[ak+3][ar+64] = a1.w;
    Bs[ak+0][ar]    = w0.x; Bs[ak+1][ar]    = w0.y; Bs[ak+2][ar]    = w0.z; Bs[ak+3][ar]    = w0.w;
    Bs[ak+0][ar+64] = w1.x; Bs[ak+1][ar+64] = w1.y; Bs[ak+2][ar+64] = w1.z; Bs[ak+3][ar+64] = w1.w;
    __syncthreads();
#pragma unroll
    for (int kk = 0; kk < 16; ++kk) {
      float4 x0 = *(const float4*)&As[kk][ty * 8];
      float4 x1 = *(const float4*)&As[kk][ty * 8 + 4];
      float4 y0 = *(const float4*)&Bs[kk][tx * 8];
      float4 y1 = *(const float4*)&Bs[kk][tx * 8 + 4];
      float av[8] = {x0.x, x0.y, x0.z, x0.w, x1.x, x1.y, x1.z, x1.w};
      float bv[8] = {y0.x, y0.y, y0.z, y0.w, y1.x, y1.y, y1.z, y1.w};
#pragma unroll
      for (int i = 0; i < 8; ++i)
#pragma unroll
        for (int j = 0; j < 8; ++j) acc[i][j] = fmaf(av[i], bv[j], acc[i][j]);
    }
  }
#pragma unroll
  for (int i = 0; i < 8; ++i) {
    size_t m = m0 + ty * 8 + i;
#pragma unroll
    for (int j4 = 0; j4 < 8; j4 += 4) {
      int n = n0 + tx * 8 + j4;
      float4 o;
      o.x = acc[i][j4+0] + bias[n+0];
      o.y = acc[i][j4+1] + bias[n+1];
      o.z = acc[i][j4+2] + bias[n+2];
      o.w = acc[i][j4+3] + bias[n+3];
      *(float4*)&C[m * N + n] = o;
    }
  }
}

// ============================================================================
// MoE up-proj: h[e][m][f] = relu(x[m,:] @ w1[e][:,f] + b1[e][f]) * gates[m][e]
// B matrix is [K][N] layout (w1[e][d][f], f contiguous). grid.z = expert.
// Gate row-scaling commutes with the down-proj GEMM.
// ============================================================================
__global__ __launch_bounds__(256) void gemm_moe1(
    const float* __restrict__ x, const float* __restrict__ w1,
    const float* __restrict__ b1, const float* __restrict__ gates,
    float* __restrict__ hbase, size_t h_estride, int e_begin) {
  __shared__ float As[16][132];
  __shared__ float Bs[16][132];
  const int tid = threadIdx.x;
  const int tx = tid & 15, ty = tid >> 4;
  const int m0 = blockIdx.y * 128, n0 = blockIdx.x * 128;
  const int ar = tid >> 2, ak = (tid & 3) * 4;
  const int kb = tid >> 4, nn = (tid & 15) * 8;
  const int e = e_begin + blockIdx.z;
  const float* W = w1 + (size_t)e * D_ * FF_;
  float acc[8][8] = {};
  for (int k0 = 0; k0 < D_; k0 += 16) {
    float4 a0 = *(const float4*)&x[(size_t)(m0 + ar) * D_ + k0 + ak];
    float4 a1 = *(const float4*)&x[(size_t)(m0 + ar + 64) * D_ + k0 + ak];
    float4 b0 = *(const float4*)&W[(size_t)(k0 + kb) * FF_ + n0 + nn];
    float4 b1v = *(const float4*)&W[(size_t)(k0 + kb) * FF_ + n0 + nn + 4];
    __syncthreads();
    As[ak+0][ar]    = a0.x; As[ak+1][ar]    = a0.y; As[ak+2][ar]    = a0.z; As[ak+3][ar]    = a0.w;
    As[ak+0][ar+64] = a1.x; As[ak+1][ar+64] = a1.y; As[ak+2][ar+64] = a1.z; As[ak+3][ar+64] = a1.w;
    *(float4*)&Bs[kb][nn]     = b0;
    *(float4*)&Bs[kb][nn + 4] = b1v;
    __syncthreads();
#pragma unroll
    for (int kk = 0; kk < 16; ++kk) {
      float4 x0 = *(const float4*)&As[kk][ty * 8];
      float4 x1 = *(const float4*)&As[kk][ty * 8 + 4];
      float4 y0 = *(const float4*)&Bs[kk][tx * 8];
      float4 y1 = *(const float4*)&Bs[kk][tx * 8 + 4];
      float av[8] = {x0.x, x0.y, x0.z, x0.w, x1.x, x1.y, x1.z, x1.w};
      float bv[8] = {y0.x, y0.y, y0.z, y0.w, y1.x, y1.y, y1.z, y1.w};
#pragma unroll
      for (int i = 0; i < 8; ++i)
#pragma unroll
        for (int j = 0; j < 8; ++j) acc[i][j] = fmaf(av[i], bv[j], acc[i][j]);
    }
  }
  const float* bb = b1 + (size_t)e * FF_;
  float* Cp = hbase + (size_t)blockIdx.z * h_estride;
#pragma unroll
  for (int i = 0; i < 8; ++i) {
    size_t m = m0 + ty * 8 + i;
    float ge = gates[m * E_ + e];
#pragma unroll
    for (int j4 = 0; j4 < 8; j4 += 4) {
      int n = n0 + tx * 8 + j4;
      float4 o;
      o.x = fmaxf(acc[i][j4+0] + bb[n+0], 0.f) * ge;
      o.y = fmaxf(acc[i][j4+1] + bb[n+1], 0.f) * ge;
      o.z = fmaxf(acc[i][j4+2] + bb[n+2], 0.f) * ge;
      o.w = fmaxf(acc[i][j4+3] + bb[n+3], 0.f) * ge;
      *(float4*)&Cp[m * FF_ + n] = o;
    }
  }
}

// ============================================================================
// MoE down-proj: ff[m][d] (+)= sum_e h[e][m][:] @ w2[e][:,d]
// Loops experts in-kernel (big path) or accumulates across launches (fallback).
// ============================================================================
__global__ __launch_bounds__(256) void gemm_moe2(
    const float* __restrict__ hbase, const float* __restrict__ w2,
    float* __restrict__ C, int e_begin, int e_count, size_t h_estride,
    int accumulate) {
  __shared__ float As[16][132];
  __shared__ float Bs[16][132];
  const int tid = threadIdx.x;
  const int tx = tid & 15, ty = tid >> 4;
  const int m0 = blockIdx.y * 128, n0 = blockIdx.x * 128;
  const int ar = tid >> 2, ak = (tid & 3) * 4;
  const int kb = tid >> 4, nn = (tid & 15) * 8;
  float acc[8][8] = {};
  for (int ee = 0; ee < e_count; ++ee) {
    const float* Ae = hbase + (size_t)ee * h_estride;
    const float* We = w2 + (size_t)(e_begin + ee) * FF_ * D_;
    for (int k0 = 0; k0 < FF_; k0 += 16) {
      float4 a0 = *(const float4*)&Ae[(size_t)(m0 + ar) * FF_ + k0 + ak];
      float4 a1 = *(const float4*)&Ae[(size_t)(m0 + ar + 64) * FF_ + k0 + ak];
      float4 b0 = *(const float4*)&We[(size_t)(k0 + kb) * D_ + n0 + nn];
      float4 b1v = *(const float4*)&We[(size_t)(k0 + kb) * D_ + n0 + nn + 4];
      __syncthreads();
      As[ak+0][ar]    = a0.x; As[ak+1][ar]    = a0.y; As[ak+2][ar]    = a0.z; As[ak+3][ar]    = a0.w;
      As[ak+0][ar+64] = a1.x; As[ak+1][ar+64] = a1.y; As[ak+2][ar+64] = a1.z; As[ak+3][ar+64] = a1.w;
      *(float4*)&Bs[kb][nn]     = b0;
      *(float4*)&Bs[kb][nn + 4] = b1v;
      __syncthreads();
#pragma unroll
      for (int kk = 0; kk < 16; ++kk) {
        float4 x0 = *(const float4*)&As[kk][ty * 8];
        float4 x1 = *(const float4*)&As[kk][ty * 8 + 4];
        float4 y0 = *(const float4*)&Bs[kk][tx * 8];
        float4 y1 = *(const float4*)&Bs[kk][tx * 8 + 4];
        float av[8] = {x0.x, x0.y, x0.z, x0.w, x1.x, x1.y, x1.z, x1.w};
        float bv[8] = {y0.x, y0.y, y0.z, y0.w, y1.x, y1.y, y1.z, y1.w};
#pragma unroll
        for (int i = 0; i < 8; ++i)
#pragma unroll
          for (int j = 0; j < 8; ++j) acc[i][j] = fmaf(av[i], bv[j], acc[i][j]);
      }
    }
  }
#pragma unroll
  for (int i = 0; i < 8; ++i) {
    size_t m = m0 + ty * 8 + i;
#pragma unroll
    for (int j4 = 0; j4 < 8; j4 += 4) {
      int n = n0 + tx * 8 + j4;
      float4 o;
      o.x = acc[i][j4+0]; o.y = acc[i][j4+1]; o.z = acc[i][j4+2]; o.w = acc[i][j4+3];
      if (accumulate) {
        float4 old = *(const float4*)&C[m * D_ + n];
        o.x += old.x; o.y += old.y; o.z += old.z; o.w += old.w;
      }
      *(float4*)&C[m * D_ + n] = o;
    }
  }
}

// ============================================================================
// Flash attention: one block per (q-tile=64, head, batch). 64x64 K/V tiles,
// online softmax. K-tile LDS buffer reused for P^T (keeps static LDS at 52KB).
// ============================================================================
__global__ __launch_bounds__(256) void attn_kernel(
    const float* __restrict__ qkv, const unsigned char* __restrict__ kpm,
    float* __restrict__ ctx) {
  __shared__ float Qt[64][68];   // [d][q]  (transposed)
  __shared__ float KPt[64][68];  // [d][k] for K^T, reused as [k][q] for P^T
  __shared__ float Vs[64][68];   // [k][d]  (row-major)
  const int tid = threadIdx.x;
  const int tx = tid & 15, ty = tid >> 4;
  const int qt = blockIdx.x, h = blockIdx.y, b = blockIdx.z;
  const size_t base = (size_t)b * S_ * (3 * D_);
  const float* Qg = qkv + base + h * 64;
  const float* Kg = qkv + base + D_ + h * 64;
  const float* Vg = qkv + base + 2 * D_ + h * 64;
  const int lr = tid >> 2;          // 0..63: tile row this thread loads
  const int lc = (tid & 3) * 16;    // 16-float chunk base within d

  {  // load Q tile transposed
    const float* srcp = &Qg[(size_t)(qt * 64 + lr) * (3 * D_) + lc];
#pragma unroll
    for (int c = 0; c < 4; ++c) {
      float4 v = *(const float4*)&srcp[c * 4];
      Qt[lc + c*4 + 0][lr] = v.x; Qt[lc + c*4 + 1][lr] = v.y;
      Qt[lc + c*4 + 2][lr] = v.z; Qt[lc + c*4 + 3][lr] = v.w;
    }
  }
  float acc[4][4] = {};
  float mrun[4], lrun[4];
#pragma unroll
  for (int i = 0; i < 4; ++i) { mrun[i] = -__builtin_inff(); lrun[i] = 0.f; }

  for (int kt = 0; kt < 16; ++kt) {
    __syncthreads();  // prev PV done (and Q-tile visible on first iter)
    {  // load K (transposed) and V (row-major) tiles
      const float* ks = &Kg[(size_t)(kt * 64 + lr) * (3 * D_) + lc];
      const float* vs = &Vg[(size_t)(kt * 64 + lr) * (3 * D_) + lc];
#pragma unroll
      for (int c = 0; c < 4; ++c) {
        float4 kv = *(const float4*)&ks[c * 4];
        KPt[lc + c*4 + 0][lr] = kv.x; KPt[lc + c*4 + 1][lr] = kv.y;
        KPt[lc + c*4 + 2][lr] = kv.z; KPt[lc + c*4 + 3][lr] = kv.w;
        float4 vv = *(const float4*)&vs[c * 4];
        *(float4*)&Vs[lr][lc + c*4] = vv;
      }
    }
    __syncthreads();
    // scores: q = ty*4+i, k = tx*4+j
    float s[4][4] = {};
#pragma unroll
    for (int d = 0; d < 64; ++d) {
      float4 qv = *(const float4*)&Qt[d][ty * 4];
      float4 kv = *(const float4*)&KPt[d][tx * 4];
      float qa[4] = {qv.x, qv.y, qv.z, qv.w};
      float ka[4] = {kv.x, kv.y, kv.z, kv.w};
#pragma unroll
      for (int i = 0; i < 4; ++i)
#pragma unroll
        for (int j = 0; j < 4; ++j) s[i][j] = fmaf(qa[i], ka[j], s[i][j]);
    }
    // scale + key-padding mask
    const unsigned char* mp = &kpm[(size_t)b * S_ + kt * 64 + tx * 4];
    bool msk[4] = {mp[0] != 0, mp[1] != 0, mp[2] != 0, mp[3] != 0};
#pragma unroll
    for (int i = 0; i < 4; ++i)
#pragma unroll
      for (int j = 0; j < 4; ++j)
        s[i][j] = msk[j] ? -__builtin_inff() : s[i][j] * 0.125f;
    // online softmax (row reduce across the 16 tx lanes)
    float tmax[4], rsum[4];
#pragma unroll
    for (int i = 0; i < 4; ++i) {
      tmax[i] = fmaxf(fmaxf(s[i][0], s[i][1]), fmaxf(s[i][2], s[i][3]));
#pragma unroll
      for (int mm = 1; mm < 16; mm <<= 1) tmax[i] = fmaxf(tmax[i], __shfl_xor(tmax[i], mm, 64));
      float mnew = fmaxf(mrun[i], tmax[i]);
      float al = (mrun[i] == -__builtin_inff()) ? 0.f : expf(mrun[i] - mnew);
      mrun[i] = mnew;
      rsum[i] = 0.f;
#pragma unroll
      for (int j = 0; j < 4; ++j) {
        float p = expf(s[i][j] - mrun[i]);
        s[i][j] = p; rsum[i] += p;
      }
#pragma unroll
      for (int mm = 1; mm < 16; mm <<= 1) rsum[i] += __shfl_xor(rsum[i], mm, 64);
      lrun[i] = lrun[i] * al + rsum[i];
#pragma unroll
      for (int j = 0; j < 4; ++j) acc[i][j] *= al;
    }
    __syncthreads();  // K^T reads done; safe to overwrite with P^T
#pragma unroll
    for (int i = 0; i < 4; ++i)
#pragma unroll
      for (int j = 0; j < 4; ++j) KPt[tx * 4 + j][ty * 4 + i] = s[i][j];
    __syncthreads();
    // PV: acc[i][j] += sum_kr P^T[kr][q] * V[kr][d]
#pragma unroll
    for (int kr = 0; kr < 64; ++kr) {
      float4 pv = *(const float4*)&KPt[kr][ty * 4];
      float4 vv = *(const float4*)&Vs[kr][tx * 4];
      float pa[4] = {pv.x, pv.y, pv.z, pv.w};
      float va[4] = {vv.x, vv.y, vv.z, vv.w};
#pragma unroll
      for (int i = 0; i < 4; ++i)
#pragma unroll
        for (int j = 0; j < 4; ++j) acc[i][j] = fmaf(pa[i], va[j], acc[i][j]);
    }
  }
  float* outp = ctx + (size_t)b * S_ * D_ + h * 64;
#pragma unroll
  for (int i = 0; i < 4; ++i) {
    float inv = 1.f / lrun[i];
    float4 o;
    o.x = acc[i][0] * inv; o.y = acc[i][1] * inv;
    o.z = acc[i][2] * inv; o.w = acc[i][3] * inv;
    *(float4*)&outp[(size_t)(qt * 64 + ty * 4 + i) * D_ + tx * 4] = o;
  }
}

// ============================================================================
// Residual add + LayerNorm. For LN2, also adds sum_e gates[m,e]*b2[e,:]
// (pass gates=nullptr for LN1). One 256-thread block per row (1024 cols).
// ============================================================================
__global__ __launch_bounds__(256) void add_ln(
    const float* __restrict__ x1, const float* __restrict__ x2,
    const float* __restrict__ gates, const float* __restrict__ b2,
    const float* __restrict__ g, const float* __restrict__ bta,
    float* __restrict__ out) {
  __shared__ float red[4];
  const int row = blockIdx.x, tid = threadIdx.x;
  const size_t off = (size_t)row * D_ + tid * 4;
  float4 a = *(const float4*)&x1[off];
  float4 c = *(const float4*)&x2[off];
  float v[4] = {a.x + c.x, a.y + c.y, a.z + c.z, a.w + c.w};
  if (gates) {
#pragma unroll
    for (int e = 0; e < E_; ++e) {
      float ge = gates[(size_t)row * E_ + e];
      float4 bb = *(const float4*)&b2[(size_t)e * D_ + tid * 4];
      v[0] += ge * bb.x; v[1] += ge * bb.y; v[2] += ge * bb.z; v[3] += ge * bb.w;
    }
  }
  float p = v[0] + v[1] + v[2] + v[3];
#pragma unroll
  for (int mm = 32; mm >= 1; mm >>= 1) p += __shfl_xor(p, mm, 64);
  if ((tid & 63) == 0) red[tid >> 6] = p;
  __syncthreads();
  float mu = (red[0] + red[1] + red[2] + red[3]) * (1.f / D_);
  __syncthreads();
  float d0 = v[0] - mu, d1 = v[1] - mu, d2 = v[2] - mu, d3 = v[3] - mu;
  float p2 = d0 * d0 + d1 * d1 + d2 * d2 + d3 * d3;
#pragma unroll
  for (int mm = 32; mm >= 1; mm >>= 1) p2 += __shfl_xor(p2, mm, 64);
  if ((tid & 63) == 0) red[tid >> 6] = p2;
  __syncthreads();
  float var = (red[0] + red[1] + red[2] + red[3]) * (1.f / D_);
  float sc = rsqrtf(var + EPS_);
  float4 gg = *(const float4*)&g[tid * 4];
  float4 bb = *(const float4*)&bta[tid * 4];
  float4 o;
  o.x = d0 * sc * gg.x + bb.x;
  o.y = d1 * sc * gg.y + bb.y;
  o.z = d2 * sc * gg.z + bb.z;
  o.w = d3 * sc * gg.w + bb.w;
  *(float4*)&out[off] = o;
}

// ============================================================================
// MoE gate: gates[m,:] = softmax(x[m,:] @ gate_w^T + gate_b). One wave per row.
// ============================================================================
__global__ __launch_bounds__(256) void gate_kernel(
    const float* __restrict__ x, const float* __restrict__ gw,
    const float* __restrict__ gb, float* __restrict__ gates) {
  const int lane = threadIdx.x & 63;
  const int row = blockIdx.x * 4 + (threadIdx.x >> 6);
  const float* xr = x + (size_t)row * D_;
  float a[E_] = {};
#pragma unroll
  for (int c = 0; c < 4; ++c) {
    float4 xv = *(const float4*)&xr[lane * 16 + c * 4];
#pragma unroll
    for (int e = 0; e < E_; ++e) {
      float4 wv = *(const float4*)&gw[(size_t)e * D_ + lane * 16 + c * 4];
      a[e] += xv.x * wv.x + xv.y * wv.y + xv.z * wv.z + xv.w * wv.w;
    }
  }
#pragma unroll
  for (int e = 0; e < E_; ++e) {
#pragma unroll
    for (int mm = 1; mm < 64; mm <<= 1) a[e] += __shfl_xor(a[e], mm, 64);
    a[e] += gb[e];
  }
  if (lane == 0) {
    float mx = a[0];
#pragma unroll
    for (int e = 1; e < E_; ++e) mx = fmaxf(mx, a[e]);
    float pr[E_], sum = 0.f;
#pragma unroll
    for (int e = 0; e < E_; ++e) { pr[e] = expf(a[e] - mx); sum += pr[e]; }
    float inv = 1.f / sum;
#pragma unroll
    for (int e = 0; e < E_; ++e) gates[(size_t)row * E_ + e] = pr[e] * inv;
  }
}

// ============================================================================
extern "C" void kernel_launch(void* const* d_in, const int* in_sizes, int n_in,
                              void* d_out, int out_size, void* d_ws, size_t ws_size,
                              hipStream_t stream) {
  (void)in_sizes; (void)n_in; (void)out_size;
  const float* src        = (const float*)d_in[0];
  const unsigned char* kpm = (const unsigned char*)d_in[1];  // all-false bools
  const float* in_proj_w  = (const float*)d_in[2];
  const float* in_proj_b  = (const float*)d_in[3];
  const float* out_proj_w = (const float*)d_in[4];
  const float* out_proj_b = (const float*)d_in[5];
  const float* gate_w     = (const float*)d_in[6];
  const float* gate_b     = (const float*)d_in[7];
  const float* w1         = (const float*)d_in[8];
  const float* b1         = (const float*)d_in[9];
  const float* w2         = (const float*)d_in[10];
  const float* b2         = (const float*)d_in[11];
  const float* ln1_g      = (const float*)d_in[12];
  const float* ln1_b      = (const float*)d_in[13];
  const float* ln2_g      = (const float*)d_in[14];
  const float* ln2_b      = (const float*)d_in[15];
  float* out = (float*)d_out;
  float* ws  = (float*)d_ws;

  // Workspace layout (floats). Persistent: x, gates, ff. "big" region is
  // reused: {qkv, ctx, attn_out} live during attention phase, then h lives
  // there during the MoE phase.
  float* x_   = ws;                          // M*D
  float* gts  = x_  + (size_t)M_ * D_;       // M*E
  float* ff   = gts + (size_t)M_ * E_;       // M*D
  float* big  = ff  + (size_t)M_ * D_;
  float* qkv  = big;                         // M*3D
  float* ctx  = qkv + (size_t)M_ * 3 * D_;   // M*D
  float* aout = ctx + (size_t)M_ * D_;       // M*D

  const size_t baseF = (size_t)M_ * D_ * 2 + (size_t)M_ * E_;
  const size_t bigBytes = (baseF + (size_t)E_ * M_ * FF_) * sizeof(float);  // ~302 MB
  const bool bigPath = ws_size >= bigBytes;

  dim3 blk(256);
  // 1. QKV projection
  gemm_bt<<<dim3(3 * D_ / 128, M_ / 128), blk, 0, stream>>>(
      src, in_proj_w, in_proj_b, qkv, 3 * D_, D_);
  // 2. fused attention -> ctx
  attn_kernel<<<dim3(S_ / 64, H_, B_), blk, 0, stream>>>(qkv, kpm, ctx);
  // 3. output projection
  gemm_bt<<<dim3(D_ / 128, M_ / 128), blk, 0, stream>>>(
      ctx, out_proj_w, out_proj_b, aout, D_, D_);
  // 4. x = LN1(src + attn_out)
  add_ln<<<M_, blk, 0, stream>>>(src, aout, nullptr, nullptr, ln1_g, ln1_b, x_);
  // 5. gates = softmax(x @ gate_w^T + gate_b)
  gate_kernel<<<M_ / 4, blk, 0, stream>>>(x_, gate_w, gate_b, gts);
  // 6/7. MoE (gate scaling folded into h; gate*b2 folded into final LN)
  if (bigPath) {
    float* h_all = big;  // [E][M][FF], overlaps dead qkv/ctx/aout
    gemm_moe1<<<dim3(FF_ / 128, M_ / 128, E_), blk, 0, stream>>>(
        x_, w1, b1, gts, h_all, (size_t)M_ * FF_, 0);
    gemm_moe2<<<dim3(D_ / 128, M_ / 128), blk, 0, stream>>>(
        h_all, w2, ff, 0, E_, (size_t)M_ * FF_, 0);
  } else {
    float* h_e = big;  // [M][FF], one expert at a time
    for (int e = 0; e < E_; ++e) {
      gemm_moe1<<<dim3(FF_ / 128, M_ / 128, 1), blk, 0, stream>>>(
          x_, w1, b1, gts, h_e, 0, e);
      gemm_moe2<<<dim3(D_ / 128, M_ / 128), blk, 0, stream>>>(
          h_e, w2, ff, e, 1, 0, e > 0);
    }
  }
  // 8. out = LN2(x + ff + sum_e gates*b2[e])
  add_ln<<<M_, blk, 0, stream>>>(x_, ff, gts, b2, ln2_g, ln2_b, out);
}

// Round 2
// 2087.738 us; speedup vs baseline: 2.6412x; 2.6412x over previous
//
#include <hip/hip_runtime.h>
#include <math.h>

// Problem constants: B=4, S=1024, D=1024, H=16, DH=64, E=8, FF=2048
#define B_   4
#define S_   1024
#define D_   1024
#define H_   16
#define DH_  64
#define E_   8
#define FF_  2048
#define M_   (B_ * S_)     // 4096 rows
#define EPS_ 1e-5f

typedef _Float16 f16;
typedef f16  f16x8 __attribute__((ext_vector_type(8)));
typedef f16  f16x4 __attribute__((ext_vector_type(4)));
typedef float f32x4 __attribute__((ext_vector_type(4)));

// ============================================================================
// fp32 -> f16 elementwise convert (8 elems/thread)
// ============================================================================
__global__ __launch_bounds__(256) void cvt_f16(
    const float* __restrict__ in, f16* __restrict__ out, int n8) {
  int i = blockIdx.x * 256 + threadIdx.x;
  if (i >= n8) return;
  float4 u = ((const float4*)in)[(size_t)i * 2];
  float4 v = ((const float4*)in)[(size_t)i * 2 + 1];
  f16x8 o;
  o[0] = (f16)u.x; o[1] = (f16)u.y; o[2] = (f16)u.z; o[3] = (f16)u.w;
  o[4] = (f16)v.x; o[5] = (f16)v.y; o[6] = (f16)v.z; o[7] = (f16)v.w;
  *(f16x8*)&out[(size_t)i * 8] = o;
}

// ============================================================================
// Transposing convert: in fp32 [z][R][C] -> out f16 [z][C][R].
// grid = (C/32, R/32, nz), 256 threads.
// ============================================================================
__global__ __launch_bounds__(256) void transpose_cvt(
    const float* __restrict__ in, f16* __restrict__ out, int R, int C) {
  __shared__ float t[32][33];
  const size_t pl = (size_t)blockIdx.z * R * C;
  in += pl; out += pl;
  const int c0 = blockIdx.x * 32, r0 = blockIdx.y * 32;
  const int tx = threadIdx.x & 31, ty = threadIdx.x >> 5;  // ty 0..7
#pragma unroll
  for (int i = 0; i < 4; ++i)
    t[ty + 8 * i][tx] = in[(size_t)(r0 + ty + 8 * i) * C + c0 + tx];
  __syncthreads();
#pragma unroll
  for (int i = 0; i < 4; ++i)
    out[(size_t)(c0 + ty + 8 * i) * R + r0 + tx] = (f16)t[tx][ty + 8 * i];
}

// ============================================================================
// MFMA f16 GEMM: C[M,N] = A[M,K] @ B[N,K]^T, 128x128 tile, BK=64, 4 waves,
// each wave 64x64 (4x4 fragments of 16x16x32). LDS rows padded to 72 halves.
// MODE 0: Cf = acc + bias (fp32 out)                      [out_proj]
// MODE 1: Ch = (f16)(acc + bias)                          [qkv]
// MODE 2: Ch = (f16)(relu(acc + b1[e]) * gate[m][e])      [moe1], z=expert
// MODE 3: Cf = sum over ecnt experts (opt. accumulate)    [moe2]
// ============================================================================
#define MODE_F32  0
#define MODE_QKV  1
#define MODE_MOE1 2
#define MODE_MOE2 3

template<int MODE>
__global__ __launch_bounds__(256) void gemm16(
    const f16* __restrict__ A, const f16* __restrict__ B,
    const float* __restrict__ bias, const float* __restrict__ gates,
    float* __restrict__ Cf, f16* __restrict__ Ch,
    int N, int K, int e0, int ecnt, int accum) {
  __shared__ f16 Ah[128][72];
  __shared__ f16 Bh[128][72];
  const int tid = threadIdx.x;
  const int wid = tid >> 6, lane = tid & 63;
  const int wm = wid >> 1, wn = wid & 1;
  const int r16 = lane & 15, kg = lane >> 4;
  const int m0 = blockIdx.y * 128, n0 = blockIdx.x * 128;
  const int sr = tid >> 1;            // staging row 0..127
  const int sc = (tid & 1) * 32;      // staging col base (halves)
  const int z = blockIdx.z;

  if (MODE == MODE_MOE1) {
    B  += (size_t)z * N * K;        // w1t plane for this expert
    Ch += (size_t)z * M_ * N;       // h plane
  }
  if (MODE == MODE_MOE2) {
    Cf += (size_t)z * M_ * N;       // ff partial plane
  }

  f32x4 acc[4][4] = {};
  const int nloop = (MODE == MODE_MOE2) ? ecnt : 1;
  for (int ee = 0; ee < nloop; ++ee) {
    const f16* Ae = A;
    const f16* Be = B;
    if (MODE == MODE_MOE2) {
      Ae = A + (size_t)(z * ecnt + ee) * M_ * K;
      Be = B + (size_t)(z * ecnt + ee) * N * K;
    }
    const f16* Ap = Ae + (size_t)(m0 + sr) * K + sc;
    const f16* Bp = Be + (size_t)(n0 + sr) * K + sc;
    for (int k0 = 0; k0 < K; k0 += 64) {
      float4 av[4], bv[4];
#pragma unroll
      for (int c = 0; c < 4; ++c) {
        av[c] = *(const float4*)&Ap[k0 + c * 8];
        bv[c] = *(const float4*)&Bp[k0 + c * 8];
      }
      __syncthreads();  // prior compute done reading LDS
#pragma unroll
      for (int c = 0; c < 4; ++c) {
        *(float4*)&Ah[sr][sc + c * 8] = av[c];
        *(float4*)&Bh[sr][sc + c * 8] = bv[c];
      }
      __syncthreads();
#pragma unroll
      for (int ks = 0; ks < 2; ++ks) {
        f16x8 af[4], bf[4];
#pragma unroll
        for (int i = 0; i < 4; ++i)
          af[i] = *(const f16x8*)&Ah[wm * 64 + i * 16 + r16][ks * 32 + kg * 8];
#pragma unroll
        for (int j = 0; j < 4; ++j)
          bf[j] = *(const f16x8*)&Bh[wn * 64 + j * 16 + r16][ks * 32 + kg * 8];
#pragma unroll
        for (int i = 0; i < 4; ++i)
#pragma unroll
          for (int j = 0; j < 4; ++j)
            acc[i][j] = __builtin_amdgcn_mfma_f32_16x16x32_f16(
                af[i], bf[j], acc[i][j], 0, 0, 0);
      }
    }
  }
  // epilogue: C/D layout col=lane&15, row=(lane>>4)*4+reg [m89-verified]
#pragma unroll
  for (int i = 0; i < 4; ++i) {
#pragma unroll
    for (int r = 0; r < 4; ++r) {
      const int row = m0 + wm * 64 + i * 16 + kg * 4 + r;
      float gsc = 0.f;
      if (MODE == MODE_MOE1) gsc = gates[(size_t)row * E_ + e0 + z];
#pragma unroll
      for (int j = 0; j < 4; ++j) {
        const int col = n0 + wn * 64 + j * 16 + r16;
        float v = acc[i][j][r];
        if (MODE == MODE_F32) {
          Cf[(size_t)row * N + col] = v + bias[col];
        } else if (MODE == MODE_QKV) {
          Ch[(size_t)row * N + col] = (f16)(v + bias[col]);
        } else if (MODE == MODE_MOE1) {
          float t = fmaxf(v + bias[(size_t)(e0 + z) * N + col], 0.f) * gsc;
          Ch[(size_t)row * N + col] = (f16)t;
        } else {  // MODE_MOE2
          float o = v;
          if (accum) o += Cf[(size_t)row * N + col];
          Cf[(size_t)row * N + col] = o;
        }
      }
    }
  }
}

// ============================================================================
// Flash attention, fp32 math, f16 qkv in / f16 ctx out. One block per
// (q-tile=64, head, batch). Moderate unrolling to avoid register spill.
// ============================================================================
__global__ __launch_bounds__(256) void attn_kernel(
    const f16* __restrict__ qkv, const unsigned char* __restrict__ kpm,
    f16* __restrict__ ctxh) {
  __shared__ float Qt[64][68];   // [d][q]
  __shared__ float KPt[64][68];  // [d][k] for K^T, reused as [k][q] for P^T
  __shared__ float Vs[64][68];   // [k][d]
  const int tid = threadIdx.x;
  const int tx = tid & 15, ty = tid >> 4;
  const int qt = blockIdx.x, h = blockIdx.y, b = blockIdx.z;
  const size_t base = (size_t)b * S_ * (3 * D_);
  const f16* Qg = qkv + base + h * 64;
  const f16* Kg = qkv + base + D_ + h * 64;
  const f16* Vg = qkv + base + 2 * D_ + h * 64;
  const int lr = tid >> 2;          // tile row this thread loads
  const int lc = (tid & 3) * 16;    // 16-half chunk base

  {  // Q tile, transposed
    const f16* sp = &Qg[(size_t)(qt * 64 + lr) * (3 * D_) + lc];
    f16x8 v0 = *(const f16x8*)&sp[0];
    f16x8 v1 = *(const f16x8*)&sp[8];
#pragma unroll
    for (int j = 0; j < 8; ++j) {
      Qt[lc + j][lr]     = (float)v0[j];
      Qt[lc + 8 + j][lr] = (float)v1[j];
    }
  }
  float acc[4][4] = {};
  float mrun[4], lrun[4];
#pragma unroll
  for (int i = 0; i < 4; ++i) { mrun[i] = -__builtin_inff(); lrun[i] = 0.f; }

  for (int kt = 0; kt < 16; ++kt) {
    __syncthreads();
    {  // K transposed, V row-major
      const f16* ksp = &Kg[(size_t)(kt * 64 + lr) * (3 * D_) + lc];
      const f16* vsp = &Vg[(size_t)(kt * 64 + lr) * (3 * D_) + lc];
      f16x8 k0 = *(const f16x8*)&ksp[0];
      f16x8 k1 = *(const f16x8*)&ksp[8];
      f16x8 w0 = *(const f16x8*)&vsp[0];
      f16x8 w1 = *(const f16x8*)&vsp[8];
#pragma unroll
      for (int j = 0; j < 8; ++j) {
        KPt[lc + j][lr]     = (float)k0[j];
        KPt[lc + 8 + j][lr] = (float)k1[j];
      }
      float4 a0 = {(float)w0[0], (float)w0[1], (float)w0[2], (float)w0[3]};
      float4 a1 = {(float)w0[4], (float)w0[5], (float)w0[6], (float)w0[7]};
      float4 a2 = {(float)w1[0], (float)w1[1], (float)w1[2], (float)w1[3]};
      float4 a3 = {(float)w1[4], (float)w1[5], (float)w1[6], (float)w1[7]};
      *(float4*)&Vs[lr][lc + 0]  = a0;
      *(float4*)&Vs[lr][lc + 4]  = a1;
      *(float4*)&Vs[lr][lc + 8]  = a2;
      *(float4*)&Vs[lr][lc + 12] = a3;
    }
    __syncthreads();
    float s[4][4] = {};
#pragma unroll 8
    for (int d = 0; d < 64; ++d) {
      float4 qv = *(const float4*)&Qt[d][ty * 4];
      float4 kv = *(const float4*)&KPt[d][tx * 4];
      float qa[4] = {qv.x, qv.y, qv.z, qv.w};
      float ka[4] = {kv.x, kv.y, kv.z, kv.w};
#pragma unroll
      for (int i = 0; i < 4; ++i)
#pragma unroll
        for (int j = 0; j < 4; ++j) s[i][j] = fmaf(qa[i], ka[j], s[i][j]);
    }
    // scale + key-padding mask
    const unsigned char* mp = &kpm[(size_t)b * S_ + kt * 64 + tx * 4];
    bool msk[4] = {mp[0] != 0, mp[1] != 0, mp[2] != 0, mp[3] != 0};
#pragma unroll
    for (int i = 0; i < 4; ++i)
#pragma unroll
      for (int j = 0; j < 4; ++j)
        s[i][j] = msk[j] ? -__builtin_inff() : s[i][j] * 0.125f;
    // online softmax (reduce across 16 tx lanes)
#pragma unroll
    for (int i = 0; i < 4; ++i) {
      float tmax = fmaxf(fmaxf(s[i][0], s[i][1]), fmaxf(s[i][2], s[i][3]));
#pragma unroll
      for (int mm = 1; mm < 16; mm <<= 1) tmax = fmaxf(tmax, __shfl_xor(tmax, mm, 64));
      float mnew = fmaxf(mrun[i], tmax);
      float al = (mrun[i] == -__builtin_inff()) ? 0.f : __expf(mrun[i] - mnew);
      mrun[i] = mnew;
      float rsum = 0.f;
#pragma unroll
      for (int j = 0; j < 4; ++j) {
        float p = __expf(s[i][j] - mnew);
        s[i][j] = p; rsum += p;
      }
#pragma unroll
      for (int mm = 1; mm < 16; mm <<= 1) rsum += __shfl_xor(rsum, mm, 64);
      lrun[i] = lrun[i] * al + rsum;
#pragma unroll
      for (int j = 0; j < 4; ++j) acc[i][j] *= al;
    }
    __syncthreads();  // done reading K^T; overwrite with P^T
#pragma unroll
    for (int i = 0; i < 4; ++i)
#pragma unroll
      for (int j = 0; j < 4; ++j) KPt[tx * 4 + j][ty * 4 + i] = s[i][j];
    __syncthreads();
#pragma unroll 8
    for (int kr = 0; kr < 64; ++kr) {
      float4 pv = *(const float4*)&KPt[kr][ty * 4];
      float4 vv = *(const float4*)&Vs[kr][tx * 4];
      float pa[4] = {pv.x, pv.y, pv.z, pv.w};
      float va[4] = {vv.x, vv.y, vv.z, vv.w};
#pragma unroll
      for (int i = 0; i < 4; ++i)
#pragma unroll
        for (int j = 0; j < 4; ++j) acc[i][j] = fmaf(pa[i], va[j], acc[i][j]);
    }
  }
  f16* outp = ctxh + (size_t)b * S_ * D_ + h * 64;
#pragma unroll
  for (int i = 0; i < 4; ++i) {
    float inv = 1.f / lrun[i];
    f16x4 o;
    o[0] = (f16)(acc[i][0] * inv); o[1] = (f16)(acc[i][1] * inv);
    o[2] = (f16)(acc[i][2] * inv); o[3] = (f16)(acc[i][3] * inv);
    *(f16x4*)&outp[(size_t)(qt * 64 + ty * 4 + i) * D_ + tx * 4] = o;
  }
}

// ============================================================================
// Residual add + LayerNorm. Sums `nparts` ff planes; optional gates·b2 term;
// optional f16 mirror of the output. One 256-thread block per row.
// ============================================================================
__global__ __launch_bounds__(256) void add_ln(
    const float* __restrict__ x1, const float* __restrict__ parts, int nparts,
    const float* __restrict__ gates, const float* __restrict__ b2,
    const float* __restrict__ g, const float* __restrict__ bta,
    float* __restrict__ out, f16* __restrict__ outh) {
  __shared__ float red[4];
  const int row = blockIdx.x, tid = threadIdx.x;
  const size_t off = (size_t)row * D_ + tid * 4;
  float4 a = *(const float4*)&x1[off];
  float v[4] = {a.x, a.y, a.z, a.w};
  for (int p = 0; p < nparts; ++p) {
    float4 c = *(const float4*)&parts[(size_t)p * M_ * D_ + off];
    v[0] += c.x; v[1] += c.y; v[2] += c.z; v[3] += c.w;
  }
  if (gates) {
#pragma unroll
    for (int e = 0; e < E_; ++e) {
      float ge = gates[(size_t)row * E_ + e];
      float4 bb = *(const float4*)&b2[(size_t)e * D_ + tid * 4];
      v[0] += ge * bb.x; v[1] += ge * bb.y; v[2] += ge * bb.z; v[3] += ge * bb.w;
    }
  }
  float p = v[0] + v[1] + v[2] + v[3];
#pragma unroll
  for (int mm = 32; mm >= 1; mm >>= 1) p += __shfl_xor(p, mm, 64);
  if ((tid & 63) == 0) red[tid >> 6] = p;
  __syncthreads();
  float mu = (red[0] + red[1] + red[2] + red[3]) * (1.f / D_);
  __syncthreads();
  float d0 = v[0] - mu, d1 = v[1] - mu, d2 = v[2] - mu, d3 = v[3] - mu;
  float p2 = d0 * d0 + d1 * d1 + d2 * d2 + d3 * d3;
#pragma unroll
  for (int mm = 32; mm >= 1; mm >>= 1) p2 += __shfl_xor(p2, mm, 64);
  if ((tid & 63) == 0) red[tid >> 6] = p2;
  __syncthreads();
  float var = (red[0] + red[1] + red[2] + red[3]) * (1.f / D_);
  float sc = rsqrtf(var + EPS_);
  float4 gg = *(const float4*)&g[tid * 4];
  float4 bb = *(const float4*)&bta[tid * 4];
  float o0 = d0 * sc * gg.x + bb.x;
  float o1 = d1 * sc * gg.y + bb.y;
  float o2 = d2 * sc * gg.z + bb.z;
  float o3 = d3 * sc * gg.w + bb.w;
  float4 o = {o0, o1, o2, o3};
  *(float4*)&out[off] = o;
  if (outh) {
    f16x4 oh; oh[0] = (f16)o0; oh[1] = (f16)o1; oh[2] = (f16)o2; oh[3] = (f16)o3;
    *(f16x4*)&outh[off] = oh;
  }
}

// ============================================================================
// MoE gate: softmax(x @ gate_w^T + gate_b). One wave per row.
// ============================================================================
__global__ __launch_bounds__(256) void gate_kernel(
    const float* __restrict__ x, const float* __restrict__ gw,
    const float* __restrict__ gb, float* __restrict__ gates) {
  const int lane = threadIdx.x & 63;
  const int row = blockIdx.x * 4 + (threadIdx.x >> 6);
  const float* xr = x + (size_t)row * D_;
  float a[E_] = {};
#pragma unroll
  for (int c = 0; c < 4; ++c) {
    float4 xv = *(const float4*)&xr[lane * 16 + c * 4];
#pragma unroll
    for (int e = 0; e < E_; ++e) {
      float4 wv = *(const float4*)&gw[(size_t)e * D_ + lane * 16 + c * 4];
      a[e] += xv.x * wv.x + xv.y * wv.y + xv.z * wv.z + xv.w * wv.w;
    }
  }
#pragma unroll
  for (int e = 0; e < E_; ++e) {
#pragma unroll
    for (int mm = 1; mm < 64; mm <<= 1) a[e] += __shfl_xor(a[e], mm, 64);
    a[e] += gb[e];
  }
  if (lane == 0) {
    float mx = a[0];
#pragma unroll
    for (int e = 1; e < E_; ++e) mx = fmaxf(mx, a[e]);
    float pr[E_], sum = 0.f;
#pragma unroll
    for (int e = 0; e < E_; ++e) { pr[e] = __expf(a[e] - mx); sum += pr[e]; }
    float inv = 1.f / sum;
#pragma unroll
    for (int e = 0; e < E_; ++e) gates[(size_t)row * E_ + e] = pr[e] * inv;
  }
}

// ============================================================================
extern "C" void kernel_launch(void* const* d_in, const int* in_sizes, int n_in,
                              void* d_out, int out_size, void* d_ws, size_t ws_size,
                              hipStream_t stream) {
  (void)in_sizes; (void)n_in; (void)out_size;
  const float* src         = (const float*)d_in[0];
  const unsigned char* kpm = (const unsigned char*)d_in[1];
  const float* in_proj_w   = (const float*)d_in[2];
  const float* in_proj_b   = (const float*)d_in[3];
  const float* out_proj_w  = (const float*)d_in[4];
  const float* out_proj_b  = (const float*)d_in[5];
  const float* gate_w      = (const float*)d_in[6];
  const float* gate_b      = (const float*)d_in[7];
  const float* w1          = (const float*)d_in[8];
  const float* b1          = (const float*)d_in[9];
  const float* w2          = (const float*)d_in[10];
  const float* b2          = (const float*)d_in[11];
  const float* ln1_g       = (const float*)d_in[12];
  const float* ln1_b       = (const float*)d_in[13];
  const float* ln2_g       = (const float*)d_in[14];
  const float* ln2_b       = (const float*)d_in[15];
  float* out = (float*)d_out;

  const size_t MD4 = (size_t)M_ * D_ * 4;          // 16 MB
  const size_t MD2 = (size_t)M_ * D_ * 2;          // 8 MB
  const size_t persist = MD4 + MD2 + (size_t)M_ * E_ * 4;
  const size_t wfull   = (size_t)E_ * D_ * FF_ * 2;   // 33.5 MB each
  const size_t phaseA  = MD2 + (size_t)3 * D_ * D_ * 2 + (size_t)D_ * D_ * 2
                       + (size_t)M_ * 3 * D_ * 2 + MD2 + MD4;   // 64 MB
  const size_t phaseBb = (size_t)E_ * M_ * FF_ * 2 + 4 * MD4;   // 192 MB
  const size_t bigBytes = persist + 2 * wfull + (phaseBb > phaseA ? phaseBb : phaseA);

  char* p = (char*)d_ws;
  float* x_  = (float*)p;  p += MD4;
  f16*   x_h = (f16*)p;    p += MD2;
  float* gts = (float*)p;  p += (size_t)M_ * E_ * 4;
  const bool big = ws_size >= bigBytes;
  f16 *w1t = nullptr, *w2t = nullptr;
  if (big) { w1t = (f16*)p; p += wfull; w2t = (f16*)p; p += wfull; }
  char* region = p;
  // phase A overlays
  f16*   src_h = (f16*)region;
  f16*   ipw   = (f16*)(region + MD2);
  f16*   opw   = (f16*)(region + MD2 + 6291456);
  f16*   qkvh  = (f16*)(region + MD2 + 6291456 + 2097152);
  f16*   ctxh  = (f16*)(region + MD2 + 6291456 + 2097152 + 25165824);
  float* aout  = (float*)(region + MD2 + 6291456 + 2097152 + 25165824 + MD2);

  dim3 blk(256);
  // --- prep: f16 conversions (and weight transposes on the big path) ---
  cvt_f16<<<2048, blk, 0, stream>>>(src, src_h, M_ * D_ / 8);
  cvt_f16<<<1536, blk, 0, stream>>>(in_proj_w, ipw, 3 * D_ * D_ / 8);
  cvt_f16<<<512,  blk, 0, stream>>>(out_proj_w, opw, D_ * D_ / 8);
  if (big) {
    transpose_cvt<<<dim3(FF_ / 32, D_ / 32, E_), blk, 0, stream>>>(w1, w1t, D_, FF_);
    transpose_cvt<<<dim3(D_ / 32, FF_ / 32, E_), blk, 0, stream>>>(w2, w2t, FF_, D_);
  }
  // --- attention phase ---
  gemm16<MODE_QKV><<<dim3(24, 32), blk, 0, stream>>>(
      src_h, ipw, in_proj_b, nullptr, nullptr, qkvh, 3 * D_, D_, 0, 0, 0);
  attn_kernel<<<dim3(S_ / 64, H_, B_), blk, 0, stream>>>(qkvh, kpm, ctxh);
  gemm16<MODE_F32><<<dim3(8, 32), blk, 0, stream>>>(
      ctxh, opw, out_proj_b, nullptr, aout, nullptr, D_, D_, 0, 0, 0);
  add_ln<<<M_, blk, 0, stream>>>(src, aout, 1, nullptr, nullptr, ln1_g, ln1_b, x_, x_h);
  gate_kernel<<<M_ / 4, blk, 0, stream>>>(x_, gate_w, gate_b, gts);
  // --- MoE phase ---
  if (big) {
    f16*   h_h = (f16*)region;                         // [E][M][FF]
    float* ff  = (float*)(region + (size_t)E_ * M_ * FF_ * 2);  // [4][M][D]
    gemm16<MODE_MOE1><<<dim3(16, 32, 8), blk, 0, stream>>>(
        x_h, w1t, b1, gts, nullptr, h_h, FF_, D_, 0, 0, 0);
    gemm16<MODE_MOE2><<<dim3(8, 32, 4), blk, 0, stream>>>(
        h_h, w2t, nullptr, nullptr, ff, nullptr, D_, FF_, 0, 2, 0);
    add_ln<<<M_, blk, 0, stream>>>(x_, ff, 4, gts, b2, ln2_g, ln2_b, out, nullptr);
  } else {
    f16*   w1tp = (f16*)region;                         // [2][FF][D]
    f16*   w2tp = (f16*)(region + 8388608);             // [2][D][FF]
    f16*   h_p  = (f16*)(region + 16777216);            // [2][M][FF]
    float* ffs  = (float*)(region + 16777216 + 33554432);  // [M][D]
    for (int pp = 0; pp < 4; ++pp) {
      transpose_cvt<<<dim3(FF_ / 32, D_ / 32, 2), blk, 0, stream>>>(
          w1 + (size_t)pp * 2 * D_ * FF_, w1tp, D_, FF_);
      transpose_cvt<<<dim3(D_ / 32, FF_ / 32, 2), blk, 0, stream>>>(
          w2 + (size_t)pp * 2 * FF_ * D_, w2tp, FF_, D_);
      gemm16<MODE_MOE1><<<dim3(16, 32, 2), blk, 0, stream>>>(
          x_h, w1tp, b1, gts, nullptr, h_p, FF_, D_, 2 * pp, 0, 0);
      gemm16<MODE_MOE2><<<dim3(8, 32, 1), blk, 0, stream>>>(
          h_p, w2tp, nullptr, nullptr, ffs, nullptr, D_, FF_, 0, 2, pp > 0);
    }
    add_ln<<<M_, blk, 0, stream>>>(x_, ffs, 1, gts, b2, ln2_g, ln2_b, out, nullptr);
  }
}

// Round 5
// 789.473 us; speedup vs baseline: 6.9846x; 2.6445x over previous
//
#include <hip/hip_runtime.h>
#include <math.h>

// Problem constants: B=4, S=1024, D=1024, H=16, DH=64, E=8, FF=2048
#define B_   4
#define S_   1024
#define D_   1024
#define H_   16
#define DH_  64
#define E_   8
#define FF_  2048
#define M_   (B_ * S_)     // 4096 rows
#define EPS_ 1e-5f

typedef _Float16 f16;
typedef f16  f16x8 __attribute__((ext_vector_type(8)));
typedef f16  f16x4 __attribute__((ext_vector_type(4)));
typedef float f32x4 __attribute__((ext_vector_type(4)));

// async global->LDS, 16B per lane. LDS dest must be wave-uniform base
// (HW writes base + lane*16); global src is per-lane.
__device__ __forceinline__ void gl_lds16(const f16* g, f16* l) {
  __builtin_amdgcn_global_load_lds(
      (const __attribute__((address_space(1))) void*)g,
      (__attribute__((address_space(3))) void*)l, 16, 0, 0);
}

// ============================================================================
// fp32 -> f16 elementwise convert (8 elems/thread)
// ============================================================================
__global__ __launch_bounds__(256) void cvt_f16(
    const float* __restrict__ in, f16* __restrict__ out, int n8) {
  int i = blockIdx.x * 256 + threadIdx.x;
  if (i >= n8) return;
  float4 u = ((const float4*)in)[(size_t)i * 2];
  float4 v = ((const float4*)in)[(size_t)i * 2 + 1];
  f16x8 o;
  o[0] = (f16)u.x; o[1] = (f16)u.y; o[2] = (f16)u.z; o[3] = (f16)u.w;
  o[4] = (f16)v.x; o[5] = (f16)v.y; o[6] = (f16)v.z; o[7] = (f16)v.w;
  *(f16x8*)&out[(size_t)i * 8] = o;
}

// ============================================================================
// Transposing convert: in fp32 [z][R][C] -> out f16 [z][C][R].
// ============================================================================
__global__ __launch_bounds__(256) void transpose_cvt(
    const float* __restrict__ in, f16* __restrict__ out, int R, int C) {
  __shared__ float t[32][33];
  const size_t pl = (size_t)blockIdx.z * R * C;
  in += pl; out += pl;
  const int c0 = blockIdx.x * 32, r0 = blockIdx.y * 32;
  const int tx = threadIdx.x & 31, ty = threadIdx.x >> 5;  // ty 0..7
#pragma unroll
  for (int i = 0; i < 4; ++i)
    t[ty + 8 * i][tx] = in[(size_t)(r0 + ty + 8 * i) * C + c0 + tx];
  __syncthreads();
#pragma unroll
  for (int i = 0; i < 4; ++i)
    out[(size_t)(c0 + ty + 8 * i) * R + r0 + tx] = (f16)t[tx][ty + 8 * i];
}

// ============================================================================
// MFMA f16 GEMM, m97 structure: C[M,N] = A[M,K] @ B[N,K]^T.
// 128x128 tile, BK=64, 4 waves, 4x4 fragments of 16x16x32.
// LDS: linear [128][64] halves (128B rows), staged via global_load_lds w=16.
// XOR swizzle (both sides, rule #21): physical 16B slot = logical ^ (row&7);
// staging pre-swizzles the per-lane GLOBAL source; reads apply the same XOR.
// ============================================================================
#define MODE_F32  0
#define MODE_QKV  1
#define MODE_MOE1 2
#define MODE_MOE2 3

template<int MODE>
__global__ __launch_bounds__(256) void gemm16(
    const f16* __restrict__ A, const f16* __restrict__ B,
    const float* __restrict__ bias, const float* __restrict__ gates,
    float* __restrict__ Cf, f16* __restrict__ Ch,
    int N, int K, int e0, int ecnt, int accum) {
  __shared__ f16 Ah[128 * 64];
  __shared__ f16 Bh[128 * 64];
  const int tid = threadIdx.x;
  const int wid = tid >> 6, lane = tid & 63;
  const int wm = wid >> 1, wn = wid & 1;
  const int r16 = lane & 15, kg = lane >> 4;
  const int m0 = blockIdx.y * 128, n0 = blockIdx.x * 128;
  const int z = blockIdx.z;
  const int srow = lane >> 3;            // row within 8-row group
  const int sslot = (lane & 7) ^ srow;   // pre-swizzled global 16B-slot

  const f16* Bb = B;
  f16* Chb = Ch;
  float* Cfb = Cf;
  if (MODE == MODE_MOE1) { Bb += (size_t)z * N * K; Chb += (size_t)z * M_ * N; }
  if (MODE == MODE_MOE2) { Cfb += (size_t)z * M_ * N; }

  char* AhB = (char*)Ah;
  char* BhB = (char*)Bh;
  const int rbA = (wm * 64 + r16) * 128;
  const int rbB = (wn * 64 + r16) * 128;
  const int sw0 = ((0 + kg) ^ (r16 & 7)) << 4;   // ks=0 swizzled byte-col
  const int sw1 = ((4 + kg) ^ (r16 & 7)) << 4;   // ks=1

  f32x4 acc[4][4] = {};
  const int nloop = (MODE == MODE_MOE2) ? ecnt : 1;
  for (int ee = 0; ee < nloop; ++ee) {
    const f16* Ae = A;
    const f16* Be = Bb;
    if (MODE == MODE_MOE2) {
      Ae = A  + (size_t)(z * ecnt + ee) * M_ * K;
      Be = B  + (size_t)(z * ecnt + ee) * N * K;
    }
    const f16* ApL = Ae + (size_t)(m0 + wid * 32 + srow) * K + sslot * 8;
    const f16* BpL = Be + (size_t)(n0 + wid * 32 + srow) * K + sslot * 8;
    for (int k0 = 0; k0 < K; k0 += 64) {
      __syncthreads();  // all waves done reading LDS from prev tile
#pragma unroll
      for (int ia = 0; ia < 4; ++ia)
        gl_lds16(ApL + (size_t)ia * 8 * K + k0, (f16*)(AhB + (wid * 4 + ia) * 1024));
#pragma unroll
      for (int ib = 0; ib < 4; ++ib)
        gl_lds16(BpL + (size_t)ib * 8 * K + k0, (f16*)(BhB + (wid * 4 + ib) * 1024));
      __syncthreads();  // vmcnt(0) drained before barrier -> data visible
#pragma unroll
      for (int ks = 0; ks < 2; ++ks) {
        const int sw = ks ? sw1 : sw0;
        f16x8 af[4], bf[4];
#pragma unroll
        for (int i = 0; i < 4; ++i)
          af[i] = *(const f16x8*)(AhB + rbA + i * 2048 + sw);
#pragma unroll
        for (int j = 0; j < 4; ++j)
          bf[j] = *(const f16x8*)(BhB + rbB + j * 2048 + sw);
#pragma unroll
        for (int i = 0; i < 4; ++i)
#pragma unroll
          for (int j = 0; j < 4; ++j)
            acc[i][j] = __builtin_amdgcn_mfma_f32_16x16x32_f16(
                af[i], bf[j], acc[i][j], 0, 0, 0);
      }
    }
  }
  // epilogue: C/D layout col=lane&15, row=(lane>>4)*4+reg
#pragma unroll
  for (int i = 0; i < 4; ++i) {
#pragma unroll
    for (int r = 0; r < 4; ++r) {
      const int row = m0 + wm * 64 + i * 16 + kg * 4 + r;
      float gsc = 0.f;
      if (MODE == MODE_MOE1) gsc = gates[(size_t)row * E_ + e0 + z];
#pragma unroll
      for (int j = 0; j < 4; ++j) {
        const int col = n0 + wn * 64 + j * 16 + r16;
        float v = acc[i][j][r];
        if (MODE == MODE_F32) {
          Cfb[(size_t)row * N + col] = v + bias[col];
        } else if (MODE == MODE_QKV) {
          Chb[(size_t)row * N + col] = (f16)(v + bias[col]);
        } else if (MODE == MODE_MOE1) {
          float t = fmaxf(v + bias[(size_t)(e0 + z) * N + col], 0.f) * gsc;
          Chb[(size_t)row * N + col] = (f16)t;
        } else {  // MODE_MOE2
          float o = v;
          if (accum) o += Cfb[(size_t)row * N + col];
          Cfb[(size_t)row * N + col] = o;
        }
      }
    }
  }
}

// ============================================================================
// MFMA flash attention. Block = 4 waves; Q-tile 64 rows (16/wave); K/V tiles
// of 64. fp32 online softmax on MFMA C-layout; P staged f16 in wave-private
// LDS. Row pads = 72 halves (144B = 9*16: b128-aligned, 4-word bank shift).
// ============================================================================
__global__ __launch_bounds__(256) void attn_kernel(
    const f16* __restrict__ qkv, const unsigned char* __restrict__ kpm,
    f16* __restrict__ ctxh) {
  __shared__ f16 Qs[64][72];
  __shared__ f16 Ks[64][72];
  __shared__ f16 VTs[64][72];   // [d][k]
  __shared__ f16 Ps[4][16][72];
  const int tid = threadIdx.x;
  const int w = tid >> 6, lane = tid & 63;
  const int cx = lane & 15, qg = lane >> 4;
  const int qt = blockIdx.x, h = blockIdx.y, b = blockIdx.z;
  const size_t base = (size_t)b * S_ * (3 * D_);
  const f16* Qg = qkv + base + h * 64;
  const f16* Kg = qkv + base + D_ + h * 64;
  const f16* Vg = qkv + base + 2 * D_ + h * 64;
  const int lr = tid >> 2, lc = (tid & 3) * 16;

  {  // stage Q row-major
    const f16* sp = &Qg[(size_t)(qt * 64 + lr) * (3 * D_) + lc];
    *(f16x8*)&Qs[lr][lc]     = *(const f16x8*)&sp[0];
    *(f16x8*)&Qs[lr][lc + 8] = *(const f16x8*)&sp[8];
  }
  __syncthreads();
  // Q frags (loop-invariant): A-frag row = lane&15 -> q row w*16+cx
  f16x8 aq0 = *(const f16x8*)&Qs[w * 16 + cx][qg * 8];
  f16x8 aq1 = *(const f16x8*)&Qs[w * 16 + cx][32 + qg * 8];

  f32x4 accO[4] = {};
  float mrun[4], lrun[4];
#pragma unroll
  for (int r = 0; r < 4; ++r) { mrun[r] = -__builtin_inff(); lrun[r] = 0.f; }

  for (int kt = 0; kt < 16; ++kt) {
    __syncthreads();  // prev iteration's PV reads done
    {  // stage K row-major + V transposed
      const f16* ksp = &Kg[(size_t)(kt * 64 + lr) * (3 * D_) + lc];
      const f16* vsp = &Vg[(size_t)(kt * 64 + lr) * (3 * D_) + lc];
      *(f16x8*)&Ks[lr][lc]     = *(const f16x8*)&ksp[0];
      *(f16x8*)&Ks[lr][lc + 8] = *(const f16x8*)&ksp[8];
      f16x8 v0 = *(const f16x8*)&vsp[0];
      f16x8 v1 = *(const f16x8*)&vsp[8];
#pragma unroll
      for (int j = 0; j < 8; ++j) {
        VTs[lc + j][lr]     = v0[j];
        VTs[lc + 8 + j][lr] = v1[j];
      }
    }
    __syncthreads();
    // QK^T: scores s[t] covers q rows (this wave) x k cols t*16+cx
    f32x4 s[4];
#pragma unroll
    for (int t = 0; t < 4; ++t) {
      f16x8 bk0 = *(const f16x8*)&Ks[t * 16 + cx][qg * 8];
      f16x8 bk1 = *(const f16x8*)&Ks[t * 16 + cx][32 + qg * 8];
      f32x4 zz = {};
      zz = __builtin_amdgcn_mfma_f32_16x16x32_f16(aq0, bk0, zz, 0, 0, 0);
      zz = __builtin_amdgcn_mfma_f32_16x16x32_f16(aq1, bk1, zz, 0, 0, 0);
      s[t] = zz;
    }
    // mask bytes for this lane's 4 k-columns
    const unsigned char* mp = &kpm[(size_t)b * S_ + kt * 64];
    bool mk[4];
#pragma unroll
    for (int t = 0; t < 4; ++t) mk[t] = mp[t * 16 + cx] != 0;
    // online softmax per accumulator row r (q = qg*4+r), reduce over 16 lanes
#pragma unroll
    for (int r = 0; r < 4; ++r) {
      float sv[4];
#pragma unroll
      for (int t = 0; t < 4; ++t)
        sv[t] = mk[t] ? -__builtin_inff() : s[t][r] * 0.125f;
      float mx = fmaxf(fmaxf(sv[0], sv[1]), fmaxf(sv[2], sv[3]));
#pragma unroll
      for (int mm = 1; mm < 16; mm <<= 1) mx = fmaxf(mx, __shfl_xor(mx, mm, 64));
      float mnew = fmaxf(mrun[r], mx);
      float al = (mrun[r] == -__builtin_inff()) ? 0.f : __expf(mrun[r] - mnew);
      float ps = 0.f;
#pragma unroll
      for (int t = 0; t < 4; ++t) {
        float p = __expf(sv[t] - mnew);
        Ps[w][qg * 4 + r][t * 16 + cx] = (f16)p;
        ps += p;
      }
#pragma unroll
      for (int mm = 1; mm < 16; mm <<= 1) ps += __shfl_xor(ps, mm, 64);
      lrun[r] = lrun[r] * al + ps;
      mrun[r] = mnew;
#pragma unroll
      for (int t = 0; t < 4; ++t) accO[t][r] *= al;
    }
    // PV: wave-private Ps (program order + lgkmcnt; no barrier needed)
    f16x8 ap0 = *(const f16x8*)&Ps[w][cx][qg * 8];
    f16x8 ap1 = *(const f16x8*)&Ps[w][cx][32 + qg * 8];
#pragma unroll
    for (int td = 0; td < 4; ++td) {
      f16x8 bv0 = *(const f16x8*)&VTs[td * 16 + cx][qg * 8];
      f16x8 bv1 = *(const f16x8*)&VTs[td * 16 + cx][32 + qg * 8];
      accO[td] = __builtin_amdgcn_mfma_f32_16x16x32_f16(ap0, bv0, accO[td], 0, 0, 0);
      accO[td] = __builtin_amdgcn_mfma_f32_16x16x32_f16(ap1, bv1, accO[td], 0, 0, 0);
    }
  }
  // out: q = qt*64 + w*16 + qg*4 + r ; d = h*64 + td*16 + cx
  f16* outp = ctxh + (size_t)b * S_ * D_ + h * 64;
#pragma unroll
  for (int r = 0; r < 4; ++r) {
    float inv = 1.f / lrun[r];
    const size_t rofs = (size_t)(qt * 64 + w * 16 + qg * 4 + r) * D_;
#pragma unroll
    for (int td = 0; td < 4; ++td)
      outp[rofs + td * 16 + cx] = (f16)(accO[td][r] * inv);
  }
}

// ============================================================================
// Residual add + LayerNorm. Sums `nparts` planes; optional gates·b2 term;
// optional f16 mirror. One block per row.
// ============================================================================
__global__ __launch_bounds__(256) void add_ln(
    const float* __restrict__ x1, const float* __restrict__ parts, int nparts,
    const float* __restrict__ gates, const float* __restrict__ b2,
    const float* __restrict__ g, const float* __restrict__ bta,
    float* __restrict__ out, f16* __restrict__ outh) {
  __shared__ float red[4];
  const int row = blockIdx.x, tid = threadIdx.x;
  const size_t off = (size_t)row * D_ + tid * 4;
  float4 a = *(const float4*)&x1[off];
  float v[4] = {a.x, a.y, a.z, a.w};
  for (int p = 0; p < nparts; ++p) {
    float4 c = *(const float4*)&parts[(size_t)p * M_ * D_ + off];
    v[0] += c.x; v[1] += c.y; v[2] += c.z; v[3] += c.w;
  }
  if (gates) {
#pragma unroll
    for (int e = 0; e < E_; ++e) {
      float ge = gates[(size_t)row * E_ + e];
      float4 bb = *(const float4*)&b2[(size_t)e * D_ + tid * 4];
      v[0] += ge * bb.x; v[1] += ge * bb.y; v[2] += ge * bb.z; v[3] += ge * bb.w;
    }
  }
  float p = v[0] + v[1] + v[2] + v[3];
#pragma unroll
  for (int mm = 32; mm >= 1; mm >>= 1) p += __shfl_xor(p, mm, 64);
  if ((tid & 63) == 0) red[tid >> 6] = p;
  __syncthreads();
  float mu = (red[0] + red[1] + red[2] + red[3]) * (1.f / D_);
  __syncthreads();
  float d0 = v[0] - mu, d1 = v[1] - mu, d2 = v[2] - mu, d3 = v[3] - mu;
  float p2 = d0 * d0 + d1 * d1 + d2 * d2 + d3 * d3;
#pragma unroll
  for (int mm = 32; mm >= 1; mm >>= 1) p2 += __shfl_xor(p2, mm, 64);
  if ((tid & 63) == 0) red[tid >> 6] = p2;
  __syncthreads();
  float var = (red[0] + red[1] + red[2] + red[3]) * (1.f / D_);
  float sc = rsqrtf(var + EPS_);
  float4 gg = *(const float4*)&g[tid * 4];
  float4 bb = *(const float4*)&bta[tid * 4];
  float o0 = d0 * sc * gg.x + bb.x;
  float o1 = d1 * sc * gg.y + bb.y;
  float o2 = d2 * sc * gg.z + bb.z;
  float o3 = d3 * sc * gg.w + bb.w;
  float4 o = {o0, o1, o2, o3};
  *(float4*)&out[off] = o;
  if (outh) {
    f16x4 oh; oh[0] = (f16)o0; oh[1] = (f16)o1; oh[2] = (f16)o2; oh[3] = (f16)o3;
    *(f16x4*)&outh[off] = oh;
  }
}

// ============================================================================
// MoE gate: softmax(x @ gate_w^T + gate_b). One wave per row.
// ============================================================================
__global__ __launch_bounds__(256) void gate_kernel(
    const float* __restrict__ x, const float* __restrict__ gw,
    const float* __restrict__ gb, float* __restrict__ gates) {
  const int lane = threadIdx.x & 63;
  const int row = blockIdx.x * 4 + (threadIdx.x >> 6);
  const float* xr = x + (size_t)row * D_;
  float a[E_] = {};
#pragma unroll
  for (int c = 0; c < 4; ++c) {
    float4 xv = *(const float4*)&xr[lane * 16 + c * 4];
#pragma unroll
    for (int e = 0; e < E_; ++e) {
      float4 wv = *(const float4*)&gw[(size_t)e * D_ + lane * 16 + c * 4];
      a[e] += xv.x * wv.x + xv.y * wv.y + xv.z * wv.z + xv.w * wv.w;
    }
  }
#pragma unroll
  for (int e = 0; e < E_; ++e) {
#pragma unroll
    for (int mm = 1; mm < 64; mm <<= 1) a[e] += __shfl_xor(a[e], mm, 64);
    a[e] += gb[e];
  }
  if (lane == 0) {
    float mx = a[0];
#pragma unroll
    for (int e = 1; e < E_; ++e) mx = fmaxf(mx, a[e]);
    float pr[E_], sum = 0.f;
#pragma unroll
    for (int e = 0; e < E_; ++e) { pr[e] = __expf(a[e] - mx); sum += pr[e]; }
    float inv = 1.f / sum;
#pragma unroll
    for (int e = 0; e < E_; ++e) gates[(size_t)row * E_ + e] = pr[e] * inv;
  }
}

// ============================================================================
extern "C" void kernel_launch(void* const* d_in, const int* in_sizes, int n_in,
                              void* d_out, int out_size, void* d_ws, size_t ws_size,
                              hipStream_t stream) {
  (void)in_sizes; (void)n_in; (void)out_size;
  const float* src         = (const float*)d_in[0];
  const unsigned char* kpm = (const unsigned char*)d_in[1];
  const float* in_proj_w   = (const float*)d_in[2];
  const float* in_proj_b   = (const float*)d_in[3];
  const float* out_proj_w  = (const float*)d_in[4];
  const float* out_proj_b  = (const float*)d_in[5];
  const float* gate_w      = (const float*)d_in[6];
  const float* gate_b      = (const float*)d_in[7];
  const float* w1          = (const float*)d_in[8];
  const float* b1          = (const float*)d_in[9];
  const float* w2          = (const float*)d_in[10];
  const float* b2          = (const float*)d_in[11];
  const float* ln1_g       = (const float*)d_in[12];
  const float* ln1_b       = (const float*)d_in[13];
  const float* ln2_g       = (const float*)d_in[14];
  const float* ln2_b       = (const float*)d_in[15];
  float* out = (float*)d_out;

  const size_t MD4 = (size_t)M_ * D_ * 4;          // 16 MB
  const size_t MD2 = (size_t)M_ * D_ * 2;          // 8 MB
  const size_t persist = MD4 + MD2 + (size_t)M_ * E_ * 4;
  const size_t wfull   = (size_t)E_ * D_ * FF_ * 2;            // 33.5 MB
  const size_t phaseA  = MD2 + (size_t)3 * D_ * D_ * 2 + (size_t)D_ * D_ * 2
                       + (size_t)M_ * 3 * D_ * 2 + MD2 + MD4;  // ~65 MB
  const size_t phaseBb = (size_t)E_ * M_ * FF_ * 2 + 4 * MD4;  // ~198 MB
  const size_t bigBytes = persist + 2 * wfull + (phaseBb > phaseA ? phaseBb : phaseA);

  char* p = (char*)d_ws;
  float* x_  = (float*)p;  p += MD4;
  f16*   x_h = (f16*)p;    p += MD2;
  float* gts = (float*)p;  p += (size_t)M_ * E_ * 4;
  const bool big = ws_size >= bigBytes;
  f16 *w1t = nullptr, *w2t = nullptr;
  if (big) { w1t = (f16*)p; p += wfull; w2t = (f16*)p; p += wfull; }
  char* region = p;
  // phase A overlays
  f16*   src_h = (f16*)region;
  f16*   ipw   = (f16*)(region + MD2);
  f16*   opw   = (f16*)(region + MD2 + 6291456);
  f16*   qkvh  = (f16*)(region + MD2 + 6291456 + 2097152);
  f16*   ctxh  = (f16*)(region + MD2 + 6291456 + 2097152 + 25165824);
  float* aout  = (float*)(region + MD2 + 6291456 + 2097152 + 25165824 + MD2);

  dim3 blk(256);
  // --- prep ---
  cvt_f16<<<2048, blk, 0, stream>>>(src, src_h, M_ * D_ / 8);
  cvt_f16<<<1536, blk, 0, stream>>>(in_proj_w, ipw, 3 * D_ * D_ / 8);
  cvt_f16<<<512,  blk, 0, stream>>>(out_proj_w, opw, D_ * D_ / 8);
  if (big) {
    transpose_cvt<<<dim3(FF_ / 32, D_ / 32, E_), blk, 0, stream>>>(w1, w1t, D_, FF_);
    transpose_cvt<<<dim3(D_ / 32, FF_ / 32, E_), blk, 0, stream>>>(w2, w2t, FF_, D_);
  }
  // --- attention phase ---
  gemm16<MODE_QKV><<<dim3(24, 32), blk, 0, stream>>>(
      src_h, ipw, in_proj_b, nullptr, nullptr, qkvh, 3 * D_, D_, 0, 0, 0);
  attn_kernel<<<dim3(S_ / 64, H_, B_), blk, 0, stream>>>(qkvh, kpm, ctxh);
  gemm16<MODE_F32><<<dim3(8, 32), blk, 0, stream>>>(
      ctxh, opw, out_proj_b, nullptr, aout, nullptr, D_, D_, 0, 0, 0);
  add_ln<<<M_, blk, 0, stream>>>(src, aout, 1, nullptr, nullptr, ln1_g, ln1_b, x_, x_h);
  gate_kernel<<<M_ / 4, blk, 0, stream>>>(x_, gate_w, gate_b, gts);
  // --- MoE phase ---
  if (big) {
    f16*   h_h = (f16*)region;                                   // [E][M][FF]
    float* ff  = (float*)(region + (size_t)E_ * M_ * FF_ * 2);   // [4][M][D]
    gemm16<MODE_MOE1><<<dim3(16, 32, 8), blk, 0, stream>>>(
        x_h, w1t, b1, gts, nullptr, h_h, FF_, D_, 0, 0, 0);
    gemm16<MODE_MOE2><<<dim3(8, 32, 4), blk, 0, stream>>>(
        h_h, w2t, nullptr, nullptr, ff, nullptr, D_, FF_, 0, 2, 0);
    add_ln<<<M_, blk, 0, stream>>>(x_, ff, 4, gts, b2, ln2_g, ln2_b, out, nullptr);
  } else {
    f16*   w1tp = (f16*)region;                           // [2][FF][D]   8 MB
    f16*   w2tp = (f16*)(region + 8388608);               // [2][D][FF]   8 MB
    f16*   h_p  = (f16*)(region + 16777216);              // [2][M][FF] 33.5 MB
    float* ffp  = (float*)(region + 16777216 + 33554432); // [2][M][D]   32 MB
    for (int pp = 0; pp < 4; ++pp) {
      transpose_cvt<<<dim3(FF_ / 32, D_ / 32, 2), blk, 0, stream>>>(
          w1 + (size_t)pp * 2 * D_ * FF_, w1tp, D_, FF_);
      transpose_cvt<<<dim3(D_ / 32, FF_ / 32, 2), blk, 0, stream>>>(
          w2 + (size_t)pp * 2 * FF_ * D_, w2tp, FF_, D_);
      gemm16<MODE_MOE1><<<dim3(16, 32, 2), blk, 0, stream>>>(
          x_h, w1tp, b1, gts, nullptr, h_p, FF_, D_, 2 * pp, 0, 0);
      gemm16<MODE_MOE2><<<dim3(8, 32, 2), blk, 0, stream>>>(
          h_p, w2tp, nullptr, nullptr, ffp, nullptr, D_, FF_, 0, 1, pp > 0);
    }
    add_ln<<<M_, blk, 0, stream>>>(x_, ffp, 2, gts, b2, ln2_g, ln2_b, out, nullptr);
  }
}